// Round 3
// baseline (346.748 us; speedup 1.0000x reference)
//
#include <hip/hip_runtime.h>

// SelfAttention: x(8,2048,768) fp32, W_q/W_k/W_v (768,768) fp32 -> H fp32.
// f16 MFMA pipeline, fused softmax (no standalone softmax kernel):
//   cvt -> gemm<0> Q(scaled),K -> gemm<3> Vt -> gemm<1> P'=exp(S), rowsum partials
//       -> gemm<2> H = (P'@Vt^T) * 1/rowsum
// All GEMMs: 128x128 tile, BK=64, XOR-swizzled LDS, global_load_lds(16B),
// LDS-staged coalesced epilogues. Row sums flow via rsumP[b][32][2048] (f32,
// deterministic writes, no atomics) so MODE2's K-loop is pure MFMA+LDS.

typedef _Float16 f16;
typedef __attribute__((ext_vector_type(4))) _Float16 f16x4;
typedef __attribute__((ext_vector_type(8))) _Float16 f16x8;
typedef __attribute__((ext_vector_type(4))) float    f32x4;

#define BM 128
#define BN 128
#define BKH 64                      // K-tile in halfs (128 B rows)

#define SEQ   2048
#define DIM   768
#define NBAT  8
#define MTOT  (NBAT * SEQ)          // 16384
#define XN    ((long)MTOT * DIM)    // 12582912
#define WN    (DIM * DIM)           // 589824
#define SB    ((long)SEQ * SEQ)
#define QB    ((long)SEQ * DIM)
#define XN4   3145728               // XN/4
#define WN4   147456                // WN/4

__device__ __forceinline__ void async_cp16(const void* g, void* l) {
  __builtin_amdgcn_global_load_lds((__attribute__((address_space(1))) void*)g,
                                   (__attribute__((address_space(3))) void*)l,
                                   16, 0, 0);
}

// fp32 -> f16 for x and the three weights, one launch.
__global__ void cvt_all(const float* __restrict__ x, const float* __restrict__ wq,
                        const float* __restrict__ wk, const float* __restrict__ wv,
                        f16* __restrict__ out) {
  int i = blockIdx.x * 256 + threadIdx.x;      // float4 index
  const float* src; f16* dst; int idx;
  if (i < XN4) { src = x; dst = out; idx = i; }
  else {
    int j = i - XN4;
    int w = (j < WN4) ? 0 : (j < 2 * WN4) ? 1 : 2;
    idx = j - w * WN4;
    src = (w == 0) ? wq : (w == 1) ? wk : wv;
    dst = out + XN + (long)w * WN;
  }
  float4 v = ((const float4*)src)[idx];
  f16x4 o = {(f16)v.x, (f16)v.y, (f16)v.z, (f16)v.w};
  ((f16x4*)dst)[idx] = o;
}

// NT GEMM: C[m][n] = sum_k A[m][k]*B[n][k].
// MODE 0: f16 row-major out (Q,K; z selects W/C plane; z==0 scaled by `scale`).
// MODE 1: f16 out = exp(acc); writes rowsum partials to Rsum[z][yblk*2+half][row].
// MODE 2: fp32 out = acc * (1/rowsum) read from Rsum partials.
// MODE 3: f16 transposed out Vt[b][n][m-local]. SWAP=false.
// SWAP=true calls mfma(bf,af): lane&15 = m, regs = 4 consecutive n.
// SWAP=false: lane&15 = n, regs = 4 consecutive m (natural for transposed out).
template <int MODE, bool SWAP>
__global__ __launch_bounds__(256, 4)
void gemm_nt(const f16* __restrict__ Abase, long sAz,
             const f16* __restrict__ Bbase, long sBz,
             void* __restrict__ Cbase, long sCz,
             float* __restrict__ Rsum,
             int N, int K, float scale)
{
  __shared__ __align__(16) char smem[34816];   // 32 KB staging, aliased epilogue
  __shared__ float sinv[128];                  // MODE2: per-row 1/rowsum
  f16* lA = (f16*)smem;                        // [128][64] halfs
  f16* lB = (f16*)(smem + 16384);

  const int tid  = threadIdx.x;
  const int z    = blockIdx.z;
  const int m0   = blockIdx.x * BM;
  const int n0   = blockIdx.y * BN;
  const int wave = tid >> 6;
  const int lane = tid & 63;
  const int wm   = (wave & 1) * 64;
  const int wn   = (wave >> 1) * 64;

  const f16* A = Abase + (long)z * sAz;
  const f16* B = Bbase + (long)z * sBz;

  f32x4 acc[4][4] = {};

  if constexpr (MODE == 2) {
    // 1/rowsum for this block's 128 rows, from 32 per-segment partials.
    if (tid < 128) {
      const float* rp = Rsum + (long)z * 32 * SEQ + m0 + tid;
      float s = 0.f;
#pragma unroll
      for (int k = 0; k < 32; ++k) s += rp[k * SEQ];
      sinv[tid] = 1.0f / s;
    }
    // first k-loop __syncthreads orders this write before epilogue reads
  }

  // staging: thread t loads 16B: row srow (of 32-row group p), swizzled k-chunk.
  const int srow = tid >> 3;                         // 0..31
  const int gcol = ((tid & 7) ^ (srow & 7)) * 8;     // swizzle chunk by row&7
  const f16* ga = A + (long)(m0 + srow) * K + gcol;
  const f16* gb = B + (long)(n0 + srow) * K + gcol;
  f16* la = lA + tid * 8;
  f16* lb = lB + tid * 8;

  // MFMA fragment addressing: row = lane&15 (+16i +wm), k-chunk (s*4+q)^swz
  const int frow = lane & 15;
  const int q    = lane >> 4;
  const int swz  = frow & 7;
  const int aro  = (wm + frow) * BKH;
  const int bro  = (wn + frow) * BKH;

  for (int k0 = 0; k0 < K; k0 += BKH) {
#pragma unroll
    for (int p = 0; p < 4; ++p) {
      async_cp16(ga + (long)(p * 32) * K + k0, la + p * 2048);
      async_cp16(gb + (long)(p * 32) * K + k0, lb + p * 2048);
    }
    __syncthreads();
#pragma unroll
    for (int s = 0; s < 2; ++s) {
      const int co = ((s * 4 + q) ^ swz) * 8;
      f16x8 af[4], bf[4];
#pragma unroll
      for (int i = 0; i < 4; ++i) af[i] = *(const f16x8*)&lA[aro + i * 1024 + co];
#pragma unroll
      for (int j = 0; j < 4; ++j) bf[j] = *(const f16x8*)&lB[bro + j * 1024 + co];
#pragma unroll
      for (int i = 0; i < 4; ++i)
#pragma unroll
        for (int j = 0; j < 4; ++j)
          acc[i][j] = SWAP
            ? __builtin_amdgcn_mfma_f32_16x16x32_f16(bf[j], af[i], acc[i][j], 0, 0, 0)
            : __builtin_amdgcn_mfma_f32_16x16x32_f16(af[i], bf[j], acc[i][j], 0, 0, 0);
    }
    __syncthreads();   // frag reads done before next stage overwrites
  }

  const int TS = 136;  // f16 epilogue tile stride (halfs): 272 B, 16B-aligned rows

  if constexpr (MODE == 0 || MODE == 1) {
    f16* T = (f16*)smem;   // [128][TS]
    float rs[4] = {0.f, 0.f, 0.f, 0.f};
    const float sc = (MODE == 0 && z == 0) ? scale : 1.0f;
#pragma unroll
    for (int i = 0; i < 4; ++i)
#pragma unroll
      for (int j = 0; j < 4; ++j) {
        f16x4 v;
#pragma unroll
        for (int r = 0; r < 4; ++r) {
          float xv = acc[i][j][r];
          if (MODE == 1) xv = __expf(xv); else xv *= sc;
          v[r] = (f16)xv;
          if (MODE == 1) rs[i] += (float)v[r];   // sum of f16-rounded values
        }
        *(f16x4*)&T[(wm + i * 16 + frow) * TS + wn + j * 16 + q * 4] = v;
      }
    if constexpr (MODE == 1) {
#pragma unroll
      for (int i = 0; i < 4; ++i) {
        rs[i] += __shfl_xor(rs[i], 16);
        rs[i] += __shfl_xor(rs[i], 32);   // full 64-col segment sum
      }
      if (lane < 16) {   // q==0 lanes hold the reduced sums
        float* rp = Rsum + ((long)z * 32 + blockIdx.y * 2 + (wn >> 6)) * SEQ + m0 + wm;
#pragma unroll
        for (int i = 0; i < 4; ++i) rp[i * 16 + frow] = rs[i];
      }
    }
    __syncthreads();
    f16* C = (f16*)Cbase + (long)z * sCz;
    const int row = tid >> 1, seg = (tid & 1) * 64;
#pragma unroll
    for (int k = 0; k < 8; ++k) {
      f16x8 v = *(const f16x8*)&T[row * TS + seg + k * 8];
      *(f16x8*)&C[(long)(m0 + row) * N + n0 + seg + k * 8] = v;
    }
  }

  if constexpr (MODE == 3) {   // Vt[b][d][s], SWAP=false: regs = consecutive m (=s)
    f16* T = (f16*)smem;       // [n(=d) 128][TS] holding m(=s) contiguous
#pragma unroll
    for (int i = 0; i < 4; ++i)
#pragma unroll
      for (int j = 0; j < 4; ++j) {
        f16x4 v = {(f16)acc[i][j][0], (f16)acc[i][j][1],
                   (f16)acc[i][j][2], (f16)acc[i][j][3]};
        *(f16x4*)&T[(wn + j * 16 + frow) * TS + wm + i * 16 + q * 4] = v;
      }
    __syncthreads();
    f16* C = (f16*)Cbase;
    const int b = m0 >> 11, sl = m0 & 2047;
    const int row = tid >> 1, seg = (tid & 1) * 64;
#pragma unroll
    for (int k = 0; k < 8; ++k) {
      f16x8 v = *(const f16x8*)&T[row * TS + seg + k * 8];
      *(f16x8*)&C[(long)b * QB + (long)(n0 + row) * SEQ + sl + seg + k * 8] = v;
    }
  }

  if constexpr (MODE == 2) {   // fp32 out, normalized; 2-pass (64 rows) epilogue
    float inv[4];
#pragma unroll
    for (int i = 0; i < 4; ++i) inv[i] = sinv[wm + i * 16 + frow];

    float* Tf = (float*)smem;   // [64][FS] fp32
    const int FS = 132;
    float* C = (float*)Cbase + (long)z * sCz;
    for (int pass = 0; pass < 2; ++pass) {
      if (wm == pass * 64) {
#pragma unroll
        for (int i = 0; i < 4; ++i)
#pragma unroll
          for (int j = 0; j < 4; ++j) {
            f32x4 v = acc[i][j] * inv[i];
            *(f32x4*)&Tf[(i * 16 + frow) * FS + wn + j * 16 + q * 4] = v;
          }
      }
      __syncthreads();
      const int row = tid >> 2, cs = (tid & 3) * 32;
#pragma unroll
      for (int k = 0; k < 8; ++k) {
        f32x4 v = *(const f32x4*)&Tf[row * FS + cs + k * 4];
        *(f32x4*)&C[(long)(m0 + pass * 64 + row) * N + n0 + cs + k * 4] = v;
      }
      if (pass == 0) __syncthreads();
    }
  }
}

extern "C" void kernel_launch(void* const* d_in, const int* in_sizes, int n_in,
                              void* d_out, int out_size, void* d_ws, size_t ws_size,
                              hipStream_t stream) {
  const float* x  = (const float*)d_in[0];
  const float* Wq = (const float*)d_in[1];
  const float* Wk = (const float*)d_in[2];
  const float* Wv = (const float*)d_in[3];

  f16* ws   = (f16*)d_ws;
  f16* x16  = ws;                  // XN
  f16* W16  = x16 + XN;            // 3*WN
  f16* Q16  = W16 + 3L * WN;       // XN  (pre-scaled by 1/sqrt(768))
  f16* K16  = Q16 + XN;            // XN
  f16* Vt16 = K16 + XN;            // XN   [b][d][s]
  f16* S16  = Vt16 + XN;           // NBAT*SB  (exp scores, unnormalized)
  float* rsumP = (float*)(S16 + (long)NBAT * SB);   // [8][32][2048] f32 partial rowsums

  cvt_all<<<14016, 256, 0, stream>>>(x, Wq, Wk, Wv, ws);

  dim3 blk(256);
  // Q (scaled), K projections: z in {0,1}
  gemm_nt<0, true><<<dim3(MTOT / BM, DIM / BN, 2), blk, 0, stream>>>(
      x16, 0L, W16, (long)WN, (void*)Q16, XN, nullptr, DIM, DIM, 0.03608439182435161f);
  // V projection, transposed out
  gemm_nt<3, false><<<dim3(MTOT / BM, DIM / BN, 1), blk, 0, stream>>>(
      x16, 0L, W16 + 2L * WN, 0L, (void*)Vt16, 0L, nullptr, DIM, DIM, 1.0f);
  // P' = exp(QK^T) (Q pre-scaled), f16, unnormalized + rowsum partials
  gemm_nt<1, true><<<dim3(SEQ / BM, SEQ / BN, NBAT), blk, 0, stream>>>(
      Q16, QB, K16, QB, (void*)S16, SB, rsumP, SEQ, DIM, 1.0f);
  // H = (P' @ Vt^T) / rowsum, fp32
  gemm_nt<2, true><<<dim3(SEQ / BM, DIM / BN, NBAT), blk, 0, stream>>>(
      S16, SB, Vt16, QB, d_out, QB, rsumP, DIM, SEQ, 1.0f);
}